// Round 5
// baseline (1250.000 us; speedup 1.0000x reference)
//
#include <hip/hip_runtime.h>
#include <hip/hip_bf16.h>

typedef __bf16 bf16_t;
typedef __bf16 bf16x8 __attribute__((ext_vector_type(8)));
typedef float f32x4 __attribute__((ext_vector_type(4)));

#define MFMA16(A, B, C) __builtin_amdgcn_mfma_f32_16x16x32_bf16(A, B, C, 0, 0, 0)

// Async 16B/lane global->LDS. lds base must be WAVE-UNIFORM; lane i of the wave
// deposits its 16B at ldsbase + i*16 (m97 recipe, width=16).
__device__ __forceinline__ void async_copy16(const bf16_t* g, bf16_t* l) {
    __builtin_amdgcn_global_load_lds(
        (const __attribute__((address_space(1))) void*)g,
        (__attribute__((address_space(3))) void*)l, 16, 0, 0);
}

__device__ __forceinline__ bf16x8 load8_cvt(const float* p) {
    float4 f0 = *(const float4*)p;
    float4 f1 = *(const float4*)(p + 4);
    bf16x8 v = {(bf16_t)f0.x, (bf16_t)f0.y, (bf16_t)f0.z, (bf16_t)f0.w,
                (bf16_t)f1.x, (bf16_t)f1.y, (bf16_t)f1.z, (bf16_t)f1.w};
    return v;
}

// ---------------------------------------------------------------------------
// fp32 -> bf16 bulk convert (8 elems/thread)
// ---------------------------------------------------------------------------
__global__ __launch_bounds__(256)
void cvt_f32_bf16(const float* __restrict__ src, bf16_t* __restrict__ dst, size_t n)
{
    size_t i = ((size_t)blockIdx.x * 256 + threadIdx.x) * 8;
    if (i < n) *(bf16x8*)&dst[i] = load8_cvt(&src[i]);
}

// ---------------------------------------------------------------------------
// GEMM: C[M,N] = A[M,K](bf16) @ W[N,K](fp32)^T + bias[N]
// m97 structure: A staged via global_load_lds (16B), W converted during staging.
// LDS tiles [128][32] unpadded (ds_read_b128 -> exactly 8 dwords/bank: free).
// ---------------------------------------------------------------------------
template <typename OT>
__global__ __launch_bounds__(256)
void gemm_alds(const bf16_t* __restrict__ A, const float* __restrict__ W,
               const float* __restrict__ bias, OT* __restrict__ C,
               int M, int N, int K)
{
    __shared__ __align__(16) bf16_t lds_a[128 * 32];
    __shared__ __align__(16) bf16_t lds_b[128 * 32];

    const int tid  = threadIdx.x;
    const int wave = tid >> 6;
    const int lane = tid & 63;
    const int l15  = lane & 15;
    const int quad = lane >> 4;
    const int wm   = (wave >> 1) * 64;
    const int wn   = (wave & 1) * 64;
    const int bm   = blockIdx.x * 128;
    const int bn   = blockIdx.y * 128;

    // A staging: wave stages rows [wave*32, wave*32+32), 2 instrs x 16 rows.
    const bf16_t* agp = A + (size_t)(bm + wave * 32 + (lane >> 2)) * K + (lane & 3) * 8;
    bf16_t* alp = &lds_a[wave * 32 * 32];  // wave-uniform

    f32x4 acc[4][4] = {};

    for (int k0 = 0; k0 < K; k0 += 32) {
        async_copy16(agp + k0, alp);
        async_copy16(agp + (size_t)16 * K + k0, alp + 16 * 32);
        for (int i = 0; i < 2; ++i) {
            int c = tid + i * 256;
            int row = c >> 2, col = (c & 3) * 8;
            *(bf16x8*)&lds_b[row * 32 + col] =
                load8_cvt(&W[(size_t)(bn + row) * K + k0 + col]);
        }
        __syncthreads();

        bf16x8 af[4], bfr[4];
        for (int i = 0; i < 4; ++i)
            af[i] = *(const bf16x8*)&lds_a[(wm + i * 16 + l15) * 32 + quad * 8];
        for (int j = 0; j < 4; ++j)
            bfr[j] = *(const bf16x8*)&lds_b[(wn + j * 16 + l15) * 32 + quad * 8];
        for (int i = 0; i < 4; ++i)
            for (int j = 0; j < 4; ++j)
                acc[i][j] = MFMA16(af[i], bfr[j], acc[i][j]);
        __syncthreads();
    }

    for (int i = 0; i < 4; ++i) {
        int mrow = bm + wm + i * 16 + quad * 4;
        for (int j = 0; j < 4; ++j) {
            int ncol = bn + wn + j * 16 + l15;
            float bval = bias[ncol];
            for (int r = 0; r < 4; ++r) {
                float v = acc[i][j][r] + bval;
                if constexpr (__is_same(OT, float))
                    C[(size_t)(mrow + r) * N + ncol] = v;
                else
                    C[(size_t)(mrow + r) * N + ncol] = (bf16_t)v;
            }
        }
    }
}

// ---------------------------------------------------------------------------
// RoPE in-place on Q and K (bf16), layout [B*S, H*Dh], pairs (j, j+64).
// ---------------------------------------------------------------------------
__global__ __launch_bounds__(256)
void rope_kernel(bf16_t* __restrict__ Q, bf16_t* __restrict__ Kk)
{
    size_t idx = (size_t)blockIdx.x * 256 + threadIdx.x;
    int j = (int)(idx & 63);
    size_t rest = idx >> 6;
    int h = (int)(rest & 15);
    size_t row = rest >> 4;
    int s = (int)(row & 2047);

    float inv = __expf(-(float)j * 0.14391156831212787f);  // ln(10000)/64
    float ang = (float)s * inv;
    float sn, cs;
    sincosf(ang, &sn, &cs);

    size_t base = row * 2048 + (size_t)h * 128 + j;
    float q0 = (float)Q[base], q1 = (float)Q[base + 64];
    Q[base]      = (bf16_t)(q0 * cs - q1 * sn);
    Q[base + 64] = (bf16_t)(q1 * cs + q0 * sn);
    float k0 = (float)Kk[base], k1 = (float)Kk[base + 64];
    Kk[base]      = (bf16_t)(k0 * cs - k1 * sn);
    Kk[base + 64] = (bf16_t)(k1 * cs + k0 * sn);
}

// ---------------------------------------------------------------------------
// Transpose V [B,S,H*Dh] -> Vt [B,H,Dh,S]
// ---------------------------------------------------------------------------
__global__ __launch_bounds__(256)
void transpose_v(const bf16_t* __restrict__ V, bf16_t* __restrict__ Vt)
{
    __shared__ __align__(16) bf16_t tile[64][72];
    int bh = blockIdx.z;
    int b = bh >> 4, h = bh & 15;
    int t0 = blockIdx.x * 64;
    int d0 = blockIdx.y * 64;
    int tid = threadIdx.x;

    for (int i = 0; i < 2; ++i) {
        int c = tid + i * 256;
        int row = c >> 3, col = (c & 7) * 8;
        *(uint4*)&tile[row][col] =
            *(const uint4*)&V[((size_t)(b * 2048 + t0 + row)) * 2048 + h * 128 + d0 + col];
    }
    __syncthreads();
    for (int i = 0; i < 2; ++i) {
        int c = tid + i * 256;
        int drow = c >> 3, tcol = (c & 7) * 8;
        __align__(16) bf16_t tmp[8];
        for (int j = 0; j < 8; ++j) tmp[j] = tile[tcol + j][drow];
        *(uint4*)&Vt[((size_t)((b * 16 + h) * 128 + d0 + drow)) * 2048 + t0 + tcol] =
            *(uint4*)tmp;
    }
}

// ---------------------------------------------------------------------------
// Flash attention v2: global_load_lds staging (panel layouts), shuffle softmax,
// triple-buffered K/V tiles -> ONE barrier per K-tile.
// grid: (S/64, B*H), 256 thr. Wave w owns q rows [w*16, w*16+16).
// ---------------------------------------------------------------------------
__global__ __launch_bounds__(256)
void flash_attn(const bf16_t* __restrict__ Q, const bf16_t* __restrict__ Kg,
                const bf16_t* __restrict__ Vt, bf16_t* __restrict__ Ctx)
{
    constexpr int S = 2048, H = 16, Dh = 128, D = 2048;
    constexpr float scale = 0.08838834764831845f;  // 1/sqrt(128)

    // Panel layouts: 32-elem (64B) rows => b128 frag reads hit 8 dwords/bank.
    __shared__ __align__(16) bf16_t q_lds[4][64 * 32];     // panel ks: cols [ks*32,+32)
    __shared__ __align__(16) bf16_t k_lds[3][4][32 * 32];  // buf, panel, [key][32]
    __shared__ __align__(16) bf16_t vt_lds[3][128 * 32];   // buf, [d][key-local]
    __shared__ __align__(16) bf16_t p_lds[4][16 * 40];     // per-wave P

    const int bh = blockIdx.y;
    const int b = bh >> 4, h = bh & 15;
    const int q0 = blockIdx.x * 64;
    const int tid = threadIdx.x, wave = tid >> 6, lane = tid & 63;
    const int l15 = lane & 15, quad = lane >> 4;

    const bf16_t* Qh  = Q  + ((size_t)b * S) * D + h * Dh;
    const bf16_t* Kh  = Kg + ((size_t)b * S) * D + h * Dh;
    const bf16_t* Vth = Vt + ((size_t)(b * H + h)) * Dh * S;

    // ---- stage Q (wave stages panel `wave`: 4 instrs x 16 rows) ----
    {
        const bf16_t* qg = Qh + (size_t)(q0 + (lane >> 2)) * D + wave * 32 + (lane & 3) * 8;
        bf16_t* ql = &q_lds[wave][0];
        for (int t = 0; t < 4; ++t)
            async_copy16(qg + (size_t)(t * 16) * D, ql + t * 16 * 32);
    }
    // ---- stage K/V tile 0 into buf 0 ----
    {
        const bf16_t* kg = Kh + (size_t)(lane >> 2) * D + wave * 32 + (lane & 3) * 8;
        bf16_t* kl = &k_lds[0][wave][0];
        async_copy16(kg, kl);
        async_copy16(kg + (size_t)16 * D, kl + 16 * 32);
        const bf16_t* vg = Vth + (size_t)(wave * 32 + (lane >> 2)) * S + (lane & 3) * 8;
        bf16_t* vl = &vt_lds[0][wave * 32 * 32];
        async_copy16(vg, vl);
        async_copy16(vg + (size_t)16 * S, vl + 16 * 32);
    }
    __syncthreads();

    bf16x8 aq[4];
    for (int ks = 0; ks < 4; ++ks)
        aq[ks] = *(const bf16x8*)&q_lds[ks][(wave * 16 + l15) * 32 + quad * 8];

    float m_i[4], l_i[4];
    for (int r = 0; r < 4; ++r) { m_i[r] = -30000.0f; l_i[r] = 0.0f; }
    f32x4 O[8] = {};

    int buf = 0;
    for (int kt = 0; kt < S / 32; ++kt) {
        // ---- S = Q K^T (rows quad*4+r, keys l15 / 16+l15) ----
        f32x4 sf0 = {}, sf1 = {};
        for (int ks = 0; ks < 4; ++ks) {
            bf16x8 b0 = *(const bf16x8*)&k_lds[buf][ks][l15 * 32 + quad * 8];
            bf16x8 b1 = *(const bf16x8*)&k_lds[buf][ks][(16 + l15) * 32 + quad * 8];
            sf0 = MFMA16(aq[ks], b0, sf0);
            sf1 = MFMA16(aq[ks], b1, sf1);
        }

        // ---- prefetch tile kt+1 into buf+1 (latency hidden by softmax) ----
        int nbuf = buf + 1; if (nbuf == 3) nbuf = 0;
        if (kt + 1 < S / 32) {
            int kn = (kt + 1) * 32;
            const bf16_t* kg = Kh + (size_t)(kn + (lane >> 2)) * D + wave * 32 + (lane & 3) * 8;
            bf16_t* kl = &k_lds[nbuf][wave][0];
            async_copy16(kg, kl);
            async_copy16(kg + (size_t)16 * D, kl + 16 * 32);
            const bf16_t* vg = Vth + (size_t)(wave * 32 + (lane >> 2)) * S + kn + (lane & 3) * 8;
            bf16_t* vl = &vt_lds[nbuf][wave * 32 * 32];
            async_copy16(vg, vl);
            async_copy16(vg + (size_t)16 * S, vl + 16 * 32);
        }

        // ---- online softmax (shuffle reduce across l15 = keys) ----
        for (int r = 0; r < 4; ++r) {
            float s0 = sf0[r] * scale, s1 = sf1[r] * scale;
            float mx = fmaxf(s0, s1);
            for (int mm = 8; mm >= 1; mm >>= 1) mx = fmaxf(mx, __shfl_xor(mx, mm));
            float mnew  = fmaxf(m_i[r], mx);
            float alpha = __expf(m_i[r] - mnew);
            bf16_t p0 = (bf16_t)__expf(s0 - mnew);
            bf16_t p1 = (bf16_t)__expf(s1 - mnew);
            float rs = (float)p0 + (float)p1;  // sum exactly what PV consumes
            for (int mm = 8; mm >= 1; mm >>= 1) rs += __shfl_xor(rs, mm);
            l_i[r] = l_i[r] * alpha + rs;
            m_i[r] = mnew;
            for (int j = 0; j < 8; ++j) O[j][r] *= alpha;
            p_lds[wave][(quad * 4 + r) * 40 + l15]      = p0;
            p_lds[wave][(quad * 4 + r) * 40 + 16 + l15] = p1;
        }

        // ONE barrier: P handoff + staged tile complete + WAR safe (3 bufs).
        __syncthreads();

        // ---- O += P V ----
        bf16x8 ap = *(const bf16x8*)&p_lds[wave][l15 * 40 + quad * 8];
        for (int j = 0; j < 8; ++j) {
            bf16x8 bv = *(const bf16x8*)&vt_lds[buf][(j * 16 + l15) * 32 + quad * 8];
            O[j] = MFMA16(ap, bv, O[j]);
        }
        buf = nbuf;
    }

    for (int r = 0; r < 4; ++r) {
        float linv = 1.0f / l_i[r];
        size_t row = q0 + wave * 16 + quad * 4 + r;
        for (int j = 0; j < 8; ++j)
            Ctx[((size_t)b * S + row) * D + h * Dh + j * 16 + l15] =
                (bf16_t)(O[j][r] * linv);
    }
}

// ---------------------------------------------------------------------------
extern "C" void kernel_launch(void* const* d_in, const int* in_sizes, int n_in,
                              void* d_out, int out_size, void* d_ws, size_t ws_size,
                              hipStream_t stream)
{
    const float* x  = (const float*)d_in[0];
    const float* wq = (const float*)d_in[1];
    const float* bq = (const float*)d_in[2];
    const float* wk = (const float*)d_in[3];
    const float* bk = (const float*)d_in[4];
    const float* wv = (const float*)d_in[5];
    const float* bv = (const float*)d_in[6];
    const float* wo = (const float*)d_in[7];
    const float* bo = (const float*)d_in[8];
    float* out = (float*)d_out;

    const int B = 4, S = 2048, D = 2048, H = 16, Dh = 128;
    const int M = B * S;
    const size_t elems = (size_t)M * D;  // 16,777,216

    // ws (proven size): Q | K | V(->Ctx) = 96 MiB of bf16.
    bf16_t* Qw  = (bf16_t*)d_ws;
    bf16_t* Kw  = Qw + elems;
    bf16_t* Vw  = Kw + elems;
    bf16_t* Ctx = Vw;                                  // V dead after transpose
    // d_out (67.1 MB fp32) as scratch: Vt in [0, 33.5MB), xb in [33.5, 67MB).
    // Timeline: xb conv -> QKV GEMMs (read xb) -> transpose (write Vt) ->
    // flash (read Vt) -> final GEMM (overwrite all of d_out). No overlap.
    bf16_t* Vtw = (bf16_t*)d_out;
    bf16_t* xb  = (bf16_t*)d_out + elems;

    cvt_f32_bf16<<<(int)(elems / 8 / 256), 256, 0, stream>>>(x, xb, elems);

    dim3 gGemm(M / 128, D / 128);
    gemm_alds<bf16_t><<<gGemm, 256, 0, stream>>>(xb, wq, bq, Qw, M, D, D);
    gemm_alds<bf16_t><<<gGemm, 256, 0, stream>>>(xb, wk, bk, Kw, M, D, D);
    gemm_alds<bf16_t><<<gGemm, 256, 0, stream>>>(xb, wv, bv, Vw, M, D, D);

    size_t nrope = (size_t)M * H * 64;
    rope_kernel<<<(int)(nrope / 256), 256, 0, stream>>>(Qw, Kw);

    dim3 gT(S / 64, Dh / 64, B * H);
    transpose_v<<<gT, 256, 0, stream>>>(Vw, Vtw);

    dim3 gA(S / 64, B * H);
    flash_attn<<<gA, 256, 0, stream>>>(Qw, Kw, Vtw, Ctx);

    gemm_alds<float><<<gGemm, 256, 0, stream>>>(Ctx, wo, bo, out, M, D, D);
}